// Round 11
// baseline (699.356 us; speedup 1.0000x reference)
//
#include <hip/hip_runtime.h>
#include <hip/hip_fp16.h>
#include <cstdint>

#define H 64
#define NB 120   // partition blocks per graph (pass A/C chunking)

__device__ __forceinline__ float selu_f(float x) {
  const float sc = 1.0507009873554805f;
  const float al = 1.6732632423543772f;
  return x > 0.f ? sc * x : sc * al * (expf(x) - 1.f);
}

// ---------- merged dual GEMM for both node sets (one launch per layer) ----------
__global__ __launch_bounds__(256) void gemm64_dual2(
    const float* __restrict__ Au, const float* __restrict__ Am,
    const float* __restrict__ W0u, const float* __restrict__ b0u,
    const float* __restrict__ W1u, const float* __restrict__ b1u,
    const float* __restrict__ W0m, const float* __restrict__ b0m,
    const float* __restrict__ W1m, const float* __restrict__ b1m,
    __half* __restrict__ C0u, float* __restrict__ C1u,
    __half* __restrict__ C0m, float* __restrict__ C1m,
    int Nu, int Nm, int split) {
  __shared__ float Ws0[64 * 64];
  __shared__ float Ws1[64 * 64];
  __shared__ float As[64][65];
  __shared__ float bs0[64], bs1[64];

  const float *A, *W0, *b0, *W1, *b1;
  __half* C0; float* C1; int N, blk;
  if (blockIdx.x < split) {
    A = Au; W0 = W0u; b0 = b0u; W1 = W1u; b1 = b1u;
    C0 = C0u; C1 = C1u; N = Nu; blk = blockIdx.x;
  } else {
    A = Am; W0 = W0m; b0 = b0m; W1 = W1m; b1 = b1m;
    C0 = C0m; C1 = C1m; N = Nm; blk = blockIdx.x - split;
  }

  const int tid = threadIdx.x;
  for (int i = tid; i < 1024; i += 256) {
    ((float4*)Ws0)[i] = ((const float4*)W0)[i];
    ((float4*)Ws1)[i] = ((const float4*)W1)[i];
  }
  if (tid < 64) { bs0[tid] = b0[tid]; bs1[tid] = b1[tid]; }

  const int row0 = blk * 64;
  for (int i = tid; i < 1024; i += 256) {
    int r = i >> 4, c4 = i & 15;
    int row = row0 + r;
    float4 v = make_float4(0.f, 0.f, 0.f, 0.f);
    if (row < N) v = ((const float4*)(A + (size_t)row * H))[c4];
    As[r][c4 * 4 + 0] = v.x;
    As[r][c4 * 4 + 1] = v.y;
    As[r][c4 * 4 + 2] = v.z;
    As[r][c4 * 4 + 3] = v.w;
  }
  __syncthreads();

  const int g = tid & 3;
  const int r = tid >> 2;
  float a0[16], a1[16];
#pragma unroll
  for (int j = 0; j < 16; ++j) { a0[j] = bs0[g * 16 + j]; a1[j] = bs1[g * 16 + j]; }

  for (int k = 0; k < 64; ++k) {
    float ak = As[r][k];
    const float4* w0r = (const float4*)&Ws0[k * 64 + g * 16];
    const float4* w1r = (const float4*)&Ws1[k * 64 + g * 16];
#pragma unroll
    for (int j4 = 0; j4 < 4; ++j4) {
      float4 w0 = w0r[j4], w1 = w1r[j4];
      a0[j4 * 4 + 0] += ak * w0.x; a0[j4 * 4 + 1] += ak * w0.y;
      a0[j4 * 4 + 2] += ak * w0.z; a0[j4 * 4 + 3] += ak * w0.w;
      a1[j4 * 4 + 0] += ak * w1.x; a1[j4 * 4 + 1] += ak * w1.y;
      a1[j4 * 4 + 2] += ak * w1.z; a1[j4 * 4 + 3] += ak * w1.w;
    }
  }

  const int row = row0 + r;
  if (row < N) {
    unsigned pu[8];
#pragma unroll
    for (int j2 = 0; j2 < 8; ++j2) {
      __half2 t = __floats2half2_rn(a0[2 * j2], a0[2 * j2 + 1]);
      pu[j2] = *(unsigned*)&t;
    }
    uint4* c0 = (uint4*)(C0 + (size_t)row * H + g * 16);
    c0[0] = make_uint4(pu[0], pu[1], pu[2], pu[3]);
    c0[1] = make_uint4(pu[4], pu[5], pu[6], pu[7]);

    float4* c1 = (float4*)(C1 + (size_t)row * H + g * 16);
#pragma unroll
    for (int j4 = 0; j4 < 4; ++j4) {
      c1[j4] = make_float4(a1[j4 * 4 + 0], a1[j4 * 4 + 1], a1[j4 * 4 + 2], a1[j4 * 4 + 3]);
    }
  }
}

// ---------- Pass A: per-block bucket histograms (LDS only, no device atomics) ----------
__global__ __launch_bounds__(256) void bucket_hist(
    const int* __restrict__ ed1, int E1r, int n1e, int sh1, int B1, int* __restrict__ mat1,
    const int* __restrict__ ed2, int E2r, int n2e, int sh2, int B2, int* __restrict__ mat2) {
  __shared__ int hist[256];
  int b = blockIdx.x;
  const int* ed; int Er, ne, sh, Bn, blk; int* mat;
  if (b < NB) { ed = ed1; Er = E1r; ne = n1e; sh = sh1; Bn = B1; mat = mat1; blk = b; }
  else { ed = ed2; Er = E2r; ne = n2e; sh = sh2; Bn = B2; mat = mat2; blk = b - NB; }
  for (int i = threadIdx.x; i < Bn; i += 256) hist[i] = 0;
  __syncthreads();
  int chunk = (ne + NB - 1) / NB;
  int lo = blk * chunk, hi = lo + chunk;
  if (hi > ne) hi = ne;
  for (int e = lo + threadIdx.x; e < hi; e += 256) {
    int d = (e < Er) ? ed[e] : (e - Er);
    atomicAdd(&hist[d >> sh], 1);  // LDS atomic
  }
  __syncthreads();
  for (int i = threadIdx.x; i < Bn; i += 256) mat[(size_t)i * NB + blk] = hist[i];
}

// ---------- scan chain ----------
__global__ __launch_bounds__(256) void scan_partial2(
    const int* __restrict__ cnt1, int n1, int* __restrict__ psum1, int* __restrict__ bsum1,
    const int* __restrict__ cnt2, int n2, int* __restrict__ psum2, int* __restrict__ bsum2,
    int split) {
  __shared__ int sh[256];
  int b = blockIdx.x;
  const int* cnt; int n; int* psum; int* bsum; int lb;
  if (b < split) { cnt = cnt1; n = n1; psum = psum1; bsum = bsum1; lb = b; }
  else { cnt = cnt2; n = n2; psum = psum2; bsum = bsum2; lb = b - split; }
  int i = lb * 256 + threadIdx.x;
  int tid = threadIdx.x;
  sh[tid] = (i < n) ? cnt[i] : 0;
  __syncthreads();
  for (int off = 1; off < 256; off <<= 1) {
    int t = (tid >= off) ? sh[tid - off] : 0;
    __syncthreads();
    if (tid >= off) sh[tid] += t;
    __syncthreads();
  }
  if (i < n) psum[i] = sh[tid];
  if (tid == 255) bsum[lb] = sh[255];
}

__global__ __launch_bounds__(256) void scan_bsums2(
    int* __restrict__ bsum1, int nb1, int* __restrict__ bsum2, int nb2) {
  __shared__ int sh[256];
  const int tid = threadIdx.x;
  for (int which = 0; which < 2; ++which) {
    int* bsum = which ? bsum2 : bsum1;
    int nb = which ? nb2 : nb1;
    int run = 0;
    for (int start = 0; start < nb; start += 256) {
      int i = start + tid;
      int v = (i < nb) ? bsum[i] : 0;
      __syncthreads();
      sh[tid] = v;
      __syncthreads();
      for (int off = 1; off < 256; off <<= 1) {
        int t = (tid >= off) ? sh[tid - off] : 0;
        __syncthreads();
        if (tid >= off) sh[tid] += t;
        __syncthreads();
      }
      if (i < nb) bsum[i] = run + sh[tid] - v;  // exclusive
      run += sh[255];
      __syncthreads();
    }
  }
}

__global__ __launch_bounds__(256) void finalize_excl2(
    const int* __restrict__ cnt1, const int* __restrict__ psum1,
    const int* __restrict__ bsum1, int n1, int* __restrict__ excl1,
    const int* __restrict__ cnt2, const int* __restrict__ psum2,
    const int* __restrict__ bsum2, int n2, int* __restrict__ excl2, int split) {
  int b = blockIdx.x;
  const int *cnt, *psum, *bsum; int n; int* excl; int lb;
  if (b < split) { cnt = cnt1; psum = psum1; bsum = bsum1; n = n1; excl = excl1; lb = b; }
  else { cnt = cnt2; psum = psum2; bsum = bsum2; n = n2; excl = excl2; lb = b - split; }
  int i = lb * 256 + threadIdx.x;
  if (i >= n) return;
  excl[i] = psum[i] + bsum[lb] - cnt[i];
}

// ---------- Pass C: partition edges into bucket order via private LDS cursors ----------
__global__ __launch_bounds__(256) void bucket_part(
    const int* __restrict__ es1, const int* __restrict__ ed1, int E1r, int n1e,
    int sh1, int B1, const int* __restrict__ excl1, unsigned* __restrict__ part1,
    const int* __restrict__ es2, const int* __restrict__ ed2, int E2r, int n2e,
    int sh2, int B2, const int* __restrict__ excl2, unsigned* __restrict__ part2) {
  __shared__ int cur[256];
  int b = blockIdx.x;
  const int *es, *ed, *excl; int Er, ne, sh, Bn, blk; unsigned* part;
  if (b < NB) { es = es1; ed = ed1; Er = E1r; ne = n1e; sh = sh1; Bn = B1; excl = excl1; part = part1; blk = b; }
  else { es = es2; ed = ed2; Er = E2r; ne = n2e; sh = sh2; Bn = B2; excl = excl2; part = part2; blk = b - NB; }
  for (int i = threadIdx.x; i < Bn; i += 256) cur[i] = excl[(size_t)i * NB + blk];
  __syncthreads();
  int chunk = (ne + NB - 1) / NB;
  int lo = blk * chunk, hi = lo + chunk;
  if (hi > ne) hi = ne;
  const unsigned lmask = (1u << sh) - 1u;
  for (int e = lo + threadIdx.x; e < hi; e += 256) {
    int s, d;
    if (e < Er) { s = es[e]; d = ed[e]; } else { s = e - Er; d = s; }
    int bkt = d >> sh;
    int pos = atomicAdd(&cur[bkt], 1);  // LDS atomic; (block,bucket) ranges disjoint
    part[pos] = (((unsigned)d & lmask) << 18) | (unsigned)s;
  }
}

// ---------- Pass D: per-bucket LDS counting sort -> row_ptr + csr + csr_dst ----------
__global__ __launch_bounds__(256) void bucket_sort(
    const unsigned* __restrict__ part1, const int* __restrict__ excl1,
    int n1e, int sh1, int B1, int nd1, int* __restrict__ rp1,
    int* __restrict__ csr1, int* __restrict__ cd1,
    const unsigned* __restrict__ part2, const int* __restrict__ excl2,
    int n2e, int sh2, int B2, int nd2, int* __restrict__ rp2,
    int* __restrict__ csr2, int* __restrict__ cd2) {
  __shared__ int cnt_s[512];
  __shared__ int scan_s[512];
  int b = blockIdx.x;
  const unsigned* part; const int* excl; int ne, sh, Bn, nd, bkt;
  int *rp, *csr, *cd;
  if (b < B1) { part = part1; excl = excl1; ne = n1e; sh = sh1; Bn = B1; nd = nd1; rp = rp1; csr = csr1; cd = cd1; bkt = b; }
  else { part = part2; excl = excl2; ne = n2e; sh = sh2; Bn = B2; nd = nd2; rp = rp2; csr = csr2; cd = cd2; bkt = b - B1; }
  const int tid = threadIdx.x;
  const int dbase = bkt << sh;
  const int R = 1 << sh;
  int rcap = nd - dbase;
  if (rcap > R) rcap = R;
  const int base = excl[(size_t)bkt * NB];
  const int endv = (bkt == Bn - 1) ? ne : excl[(size_t)(bkt + 1) * NB];

  cnt_s[tid] = 0; cnt_s[256 + tid] = 0;
  __syncthreads();
  for (int i = base + tid; i < endv; i += 256)
    atomicAdd(&cnt_s[part[i] >> 18], 1);
  __syncthreads();
  scan_s[tid] = cnt_s[tid];
  scan_s[256 + tid] = cnt_s[256 + tid];
  __syncthreads();
  for (int off = 1; off < 256; off <<= 1) {
    int t = (tid >= off) ? scan_s[tid - off] : 0;
    __syncthreads();
    if (tid >= off) scan_s[tid] += t;
    __syncthreads();
  }
  for (int off = 1; off < 256; off <<= 1) {
    int t = (tid >= off) ? scan_s[256 + tid - off] : 0;
    __syncthreads();
    if (tid >= off) scan_s[256 + tid] += t;
    __syncthreads();
  }
  int lowtot = scan_s[255];
  scan_s[256 + tid] += lowtot;
  __syncthreads();
  if (tid < rcap) rp[dbase + tid + 1] = base + scan_s[tid];
  if (256 + tid < rcap) rp[dbase + 256 + tid + 1] = base + scan_s[256 + tid];
  cnt_s[tid] = base + scan_s[tid] - cnt_s[tid];
  cnt_s[256 + tid] = base + scan_s[256 + tid] - cnt_s[256 + tid];
  if (tid == 0 && bkt == 0) rp[0] = 0;
  __syncthreads();
  for (int i = base + tid; i < endv; i += 256) {
    unsigned p = part[i];
    int dl = p >> 18;
    int pos = atomicAdd(&cnt_s[dl], 1);  // LDS atomic
    csr[pos] = (int)(p & 0x3FFFFu);
    cd[pos] = dbase + dl;
  }
}

// ---------- Phase 1: edge-parallel GATv2 scores (both graphs, CSR order) ----------
// thread-per-edge; consecutive threads share dst (CSR order) -> xr reads L1-broadcast.
// lrelu(p)*att folded: p*(0.6a) + |p|*(0.4a).
__global__ __launch_bounds__(256) void score_k(
    const int* __restrict__ cs1, const int* __restrict__ cd1,
    const __half* __restrict__ xl1, const float* __restrict__ xr1,
    const float* __restrict__ att1, float* __restrict__ sc1, int n1,
    const int* __restrict__ cs2, const int* __restrict__ cd2,
    const __half* __restrict__ xl2, const float* __restrict__ xr2,
    const float* __restrict__ att2, float* __restrict__ sc2, int n2, int split) {
  __shared__ float a06[64], a04[64];
  int b = blockIdx.x;
  const int *cs, *cd; const __half* xl; const float *xr, *att; float* sc; int n, e;
  if (b < split) {
    cs = cs1; cd = cd1; xl = xl1; xr = xr1; att = att1; sc = sc1;
    n = n1; e = b * 256 + threadIdx.x;
  } else {
    cs = cs2; cd = cd2; xl = xl2; xr = xr2; att = att2; sc = sc2;
    n = n2; e = (b - split) * 256 + threadIdx.x;
  }
  if (threadIdx.x < 64) {
    float a = att[threadIdx.x];
    a06[threadIdx.x] = 0.6f * a;
    a04[threadIdx.x] = 0.4f * a;
  }
  __syncthreads();
  if (e >= n) return;
  int s = cs[e], d = cd[e];
  const float4* rl = (const float4*)(xl + ((size_t)s << 6));  // 8 halves / float4
  const float4* rr = (const float4*)(xr + ((size_t)d << 6));
  float sum = 0.f;
#pragma unroll
  for (int c = 0; c < 8; ++c) {
    float4 hraw = rl[c];
    const __half2* hp = (const __half2*)&hraw;
    float4 r0 = rr[2 * c];
    float4 r1 = rr[2 * c + 1];
    float xrv[8] = {r0.x, r0.y, r0.z, r0.w, r1.x, r1.y, r1.z, r1.w};
#pragma unroll
    for (int u = 0; u < 4; ++u) {
      float2 xf = __half22float2(hp[u]);
      int h0 = c * 8 + u * 2;
      float p0 = xf.x + xrv[u * 2];
      float p1 = xf.y + xrv[u * 2 + 1];
      sum += p0 * a06[h0] + fabsf(p0) * a04[h0];
      sum += p1 * a06[h0 + 1] + fabsf(p1) * a04[h0 + 1];
    }
  }
  sc[e] = sum;
}

// ---------- Phase 2: per-dst softmax normalize, sc[i] <- exp(sc-m)/sum ----------
// 4 dsts per 256-block (one per wave); lane = edge slot, coalesced sc access.
__global__ __launch_bounds__(256) void norm_k(
    const int* __restrict__ rp1, float* __restrict__ sc1, int nd1,
    const int* __restrict__ rp2, float* __restrict__ sc2, int nd2, int split) {
  int b = blockIdx.x;
  const int* rp; float* sc; int nd, d0;
  if (b < split) { rp = rp1; sc = sc1; nd = nd1; d0 = b * 4; }
  else { rp = rp2; sc = sc2; nd = nd2; d0 = (b - split) * 4; }
  int w = threadIdx.x >> 6, lane = threadIdx.x & 63;
  int d = d0 + w;
  if (d >= nd) return;
  int beg = rp[d], end = rp[d + 1];
  float m = -3.0e38f, ssum = 0.f;
  for (int i0 = beg; i0 < end; i0 += 64) {
    int i = i0 + lane;
    float t = (i < end) ? sc[i] : -3.0e38f;
    float M = t;
#pragma unroll
    for (int mk = 1; mk <= 32; mk <<= 1) M = fmaxf(M, __shfl_xor(M, mk, 64));
    float e = __expf(t - M);  // 0 for invalid lanes
    float S = e;
#pragma unroll
    for (int mk = 1; mk <= 32; mk <<= 1) S += __shfl_xor(S, mk, 64);
    float nm = fmaxf(m, M);
    ssum = ssum * __expf(m - nm) + S * __expf(M - nm);
    m = nm;
  }
  float inv = 1.f / (ssum + 1e-16f);
  for (int i0 = beg; i0 < end; i0 += 64) {
    int i = i0 + lane;
    if (i < end) sc[i] = __expf(sc[i] - m) * inv;
  }
}

// ---------- Phase 3: weighted gather-aggregate + bias + SELU ----------
// 4 dsts per 256-block (one per wave); lane = feature h. 8-wide clamped unroll
// (wt=0 beyond end) keeps 8 independent gathers in flight. No LDS, no shuffles.
__global__ __launch_bounds__(256) void aggr_k(
    const int* __restrict__ rp1, const int* __restrict__ csr1,
    const float* __restrict__ sc1, const __half* __restrict__ xl1,
    const float* __restrict__ bias1, float* __restrict__ out1, int nd1,
    const int* __restrict__ rp2, const int* __restrict__ csr2,
    const float* __restrict__ sc2, const __half* __restrict__ xl2,
    const float* __restrict__ bias2, float* __restrict__ out2, int nd2, int split) {
  int b = blockIdx.x;
  const int *rp, *csr; const float* sc; const __half* xl; const float* bias;
  float* out; int nd, d0;
  if (b < split) {
    rp = rp1; csr = csr1; sc = sc1; xl = xl1; bias = bias1; out = out1;
    nd = nd1; d0 = b * 4;
  } else {
    rp = rp2; csr = csr2; sc = sc2; xl = xl2; bias = bias2; out = out2;
    nd = nd2; d0 = (b - split) * 4;
  }
  int w = threadIdx.x >> 6, h = threadIdx.x & 63;
  int d = d0 + w;
  if (d >= nd) return;
  int beg = rp[d], end = rp[d + 1];
  float acc = 0.f;
  for (int i0 = beg; i0 < end; i0 += 8) {
#pragma unroll
    for (int k = 0; k < 8; ++k) {
      int idx = i0 + k;
      bool vld = idx < end;                  // wave-uniform
      int ii = vld ? idx : end - 1;          // clamped dup
      int src = csr[ii];
      float wt = vld ? sc[ii] : 0.f;         // zero weight for dups
      acc = fmaf(wt, __half2float(xl[((size_t)src << 6) + h]), acc);
    }
  }
  out[(size_t)d * H + h] = selu_f(acc + bias[h]);
}

// ---------- launch ----------
extern "C" void kernel_launch(void* const* d_in, const int* in_sizes, int n_in,
                              void* d_out, int out_size, void* d_ws, size_t ws_size,
                              hipStream_t stream) {
  const float* x_user = (const float*)d_in[0];
  const float* x_movie = (const float*)d_in[1];
  const int* e_u2m = (const int*)d_in[2];
  const int* e_m2u = (const int*)d_in[3];
  const float* Wl = (const float*)d_in[4];
  const float* bl = (const float*)d_in[5];
  const float* Wr = (const float*)d_in[6];
  const float* br = (const float*)d_in[7];
  const float* att = (const float*)d_in[8];
  const float* bias = (const float*)d_in[9];

  const int n_user = in_sizes[0] / H;
  const int n_movie = in_sizes[1] / H;
  const int E1 = in_sizes[2] / 2;  // user->movie (dst = movie)
  const int E2 = in_sizes[3] / 2;  // movie->user (dst = user)
  const int n_loop = n_user < n_movie ? n_user : n_movie;
  const int nE1 = E1 + n_loop;
  const int nE2 = E2 + n_loop;

  const int SHM = 7, SHU = 9;
  const int Bm = (n_movie + (1 << SHM) - 1) >> SHM;
  const int Bu = (n_user + (1 << SHU) - 1) >> SHU;
  const int nmatM = Bm * NB, nmatU = Bu * NB;
  const int nbm = (nmatM + 255) / 256, nbu = (nmatU + 255) / 256;

  float* ws = (float*)d_ws;
  size_t o = 0;
  __half* xl_u2m = (__half*)(ws + o); o += (size_t)n_user * H / 2;
  __half* xl_m2u = (__half*)(ws + o); o += (size_t)n_movie * H / 2;
  float* xr_u2m = ws + o; o += (size_t)n_movie * H;
  float* xr_m2u = ws + o; o += (size_t)n_user * H;

  int* matM  = (int*)(ws + o); o += nmatM;
  int* psumM = (int*)(ws + o); o += nmatM;
  int* exclM = (int*)(ws + o); o += nmatM;
  int* matU  = (int*)(ws + o); o += nmatU;
  int* psumU = (int*)(ws + o); o += nmatU;
  int* exclU = (int*)(ws + o); o += nmatU;
  int* bsumM = (int*)(ws + o); o += 1024;
  int* bsumU = (int*)(ws + o); o += 1024;
  unsigned* partM = (unsigned*)(ws + o); o += nE1;
  unsigned* partU = (unsigned*)(ws + o); o += nE2;
  int* csr1 = (int*)(ws + o); o += nE1;
  int* csr2 = (int*)(ws + o); o += nE2;
  int* cd1  = (int*)(ws + o); o += nE1;
  int* cd2  = (int*)(ws + o); o += nE2;
  float* sc1 = ws + o; o += nE1;
  float* sc2 = ws + o; o += nE2;
  int* rp1  = (int*)(ws + o); o += n_movie + 1;
  int* rp2  = (int*)(ws + o); o += n_user + 1;

  float* out_u = (float*)d_out;
  float* out_m = out_u + (size_t)n_user * H;

  const int gu = (n_user + 63) / 64;
  const int gm = (n_movie + 63) / 64;
  const int eb1 = (nE1 + 255) / 256;     // score blocks, graph 1
  const int eb2 = (nE2 + 255) / 256;
  const int db1 = (n_movie + 3) / 4;     // dst blocks, graph 1
  const int db2 = (n_user + 3) / 4;

  // ---- CSR build: deterministic two-level bucket sort, zero device atomics ----
  bucket_hist<<<2 * NB, 256, 0, stream>>>(
      e_u2m + E1, E1, nE1, SHM, Bm, matM,
      e_m2u + E2, E2, nE2, SHU, Bu, matU);
  scan_partial2<<<nbm + nbu, 256, 0, stream>>>(
      matM, nmatM, psumM, bsumM, matU, nmatU, psumU, bsumU, nbm);
  scan_bsums2<<<1, 256, 0, stream>>>(bsumM, nbm, bsumU, nbu);
  finalize_excl2<<<nbm + nbu, 256, 0, stream>>>(
      matM, psumM, bsumM, nmatM, exclM,
      matU, psumU, bsumU, nmatU, exclU, nbm);
  bucket_part<<<2 * NB, 256, 0, stream>>>(
      e_u2m, e_u2m + E1, E1, nE1, SHM, Bm, exclM, partM,
      e_m2u, e_m2u + E2, E2, nE2, SHU, Bu, exclU, partU);
  bucket_sort<<<Bm + Bu, 256, 0, stream>>>(
      partM, exclM, nE1, SHM, Bm, n_movie, rp1, csr1, cd1,
      partU, exclU, nE2, SHU, Bu, n_user, rp2, csr2, cd2);

  for (int l = 0; l < 2; ++l) {
    const float* cu = (l == 0) ? x_user : out_u;
    const float* cm = (l == 0) ? x_movie : out_m;
    const int p0 = l * 2 + 0;  // user->movie params
    const int p1 = l * 2 + 1;  // movie->user params

    gemm64_dual2<<<gu + gm, 256, 0, stream>>>(
        cu, cm,
        Wl + (size_t)p0 * H * H, bl + (size_t)p0 * H,   // user C0 = Wl[p0] (fp16)
        Wr + (size_t)p1 * H * H, br + (size_t)p1 * H,   // user C1 = Wr[p1] (fp32)
        Wl + (size_t)p1 * H * H, bl + (size_t)p1 * H,   // movie C0 = Wl[p1] (fp16)
        Wr + (size_t)p0 * H * H, br + (size_t)p0 * H,   // movie C1 = Wr[p0] (fp32)
        xl_u2m, xr_m2u, xl_m2u, xr_u2m,
        n_user, n_movie, gu);

    score_k<<<eb1 + eb2, 256, 0, stream>>>(
        csr1, cd1, xl_u2m, xr_u2m, att + (size_t)p0 * H, sc1, nE1,
        csr2, cd2, xl_m2u, xr_m2u, att + (size_t)p1 * H, sc2, nE2, eb1);
    norm_k<<<db1 + db2, 256, 0, stream>>>(
        rp1, sc1, n_movie, rp2, sc2, n_user, db1);
    aggr_k<<<db1 + db2, 256, 0, stream>>>(
        rp1, csr1, sc1, xl_u2m, bias + (size_t)p0 * H, out_m, n_movie,
        rp2, csr2, sc2, xl_m2u, bias + (size_t)p1 * H, out_u, n_user, db1);
  }
}

// Round 12
// 482.841 us; speedup vs baseline: 1.4484x; 1.4484x over previous
//
#include <hip/hip_runtime.h>
#include <hip/hip_fp16.h>
#include <cstdint>

#define H 64
#define EPR 16   // edges per round in gat (16 -> 4KB tile/wave)
#define NB 120   // partition blocks per graph (pass A/C chunking)

__device__ __forceinline__ float selu_f(float x) {
  const float sc = 1.0507009873554805f;
  const float al = 1.6732632423543772f;
  return x > 0.f ? sc * x : sc * al * (expf(x) - 1.f);
}

// ---------- merged dual GEMM for both node sets (one launch per layer) ----------
__global__ __launch_bounds__(256) void gemm64_dual2(
    const float* __restrict__ Au, const float* __restrict__ Am,
    const float* __restrict__ W0u, const float* __restrict__ b0u,
    const float* __restrict__ W1u, const float* __restrict__ b1u,
    const float* __restrict__ W0m, const float* __restrict__ b0m,
    const float* __restrict__ W1m, const float* __restrict__ b1m,
    __half* __restrict__ C0u, float* __restrict__ C1u,
    __half* __restrict__ C0m, float* __restrict__ C1m,
    int Nu, int Nm, int split) {
  __shared__ float Ws0[64 * 64];
  __shared__ float Ws1[64 * 64];
  __shared__ float As[64][65];
  __shared__ float bs0[64], bs1[64];

  const float *A, *W0, *b0, *W1, *b1;
  __half* C0; float* C1; int N, blk;
  if (blockIdx.x < split) {
    A = Au; W0 = W0u; b0 = b0u; W1 = W1u; b1 = b1u;
    C0 = C0u; C1 = C1u; N = Nu; blk = blockIdx.x;
  } else {
    A = Am; W0 = W0m; b0 = b0m; W1 = W1m; b1 = b1m;
    C0 = C0m; C1 = C1m; N = Nm; blk = blockIdx.x - split;
  }

  const int tid = threadIdx.x;
  for (int i = tid; i < 1024; i += 256) {
    ((float4*)Ws0)[i] = ((const float4*)W0)[i];
    ((float4*)Ws1)[i] = ((const float4*)W1)[i];
  }
  if (tid < 64) { bs0[tid] = b0[tid]; bs1[tid] = b1[tid]; }

  const int row0 = blk * 64;
  for (int i = tid; i < 1024; i += 256) {
    int r = i >> 4, c4 = i & 15;
    int row = row0 + r;
    float4 v = make_float4(0.f, 0.f, 0.f, 0.f);
    if (row < N) v = ((const float4*)(A + (size_t)row * H))[c4];
    As[r][c4 * 4 + 0] = v.x;
    As[r][c4 * 4 + 1] = v.y;
    As[r][c4 * 4 + 2] = v.z;
    As[r][c4 * 4 + 3] = v.w;
  }
  __syncthreads();

  const int g = tid & 3;
  const int r = tid >> 2;
  float a0[16], a1[16];
#pragma unroll
  for (int j = 0; j < 16; ++j) { a0[j] = bs0[g * 16 + j]; a1[j] = bs1[g * 16 + j]; }

  for (int k = 0; k < 64; ++k) {
    float ak = As[r][k];
    const float4* w0r = (const float4*)&Ws0[k * 64 + g * 16];
    const float4* w1r = (const float4*)&Ws1[k * 64 + g * 16];
#pragma unroll
    for (int j4 = 0; j4 < 4; ++j4) {
      float4 w0 = w0r[j4], w1 = w1r[j4];
      a0[j4 * 4 + 0] += ak * w0.x; a0[j4 * 4 + 1] += ak * w0.y;
      a0[j4 * 4 + 2] += ak * w0.z; a0[j4 * 4 + 3] += ak * w0.w;
      a1[j4 * 4 + 0] += ak * w1.x; a1[j4 * 4 + 1] += ak * w1.y;
      a1[j4 * 4 + 2] += ak * w1.z; a1[j4 * 4 + 3] += ak * w1.w;
    }
  }

  const int row = row0 + r;
  if (row < N) {
    unsigned pu[8];
#pragma unroll
    for (int j2 = 0; j2 < 8; ++j2) {
      __half2 t = __floats2half2_rn(a0[2 * j2], a0[2 * j2 + 1]);
      pu[j2] = *(unsigned*)&t;
    }
    uint4* c0 = (uint4*)(C0 + (size_t)row * H + g * 16);
    c0[0] = make_uint4(pu[0], pu[1], pu[2], pu[3]);
    c0[1] = make_uint4(pu[4], pu[5], pu[6], pu[7]);

    float4* c1 = (float4*)(C1 + (size_t)row * H + g * 16);
#pragma unroll
    for (int j4 = 0; j4 < 4; ++j4) {
      c1[j4] = make_float4(a1[j4 * 4 + 0], a1[j4 * 4 + 1], a1[j4 * 4 + 2], a1[j4 * 4 + 3]);
    }
  }
}

// ---------- Pass A: per-block bucket histograms (LDS only, no device atomics) ----------
__global__ __launch_bounds__(256) void bucket_hist(
    const int* __restrict__ ed1, int E1r, int n1e, int sh1, int B1, int* __restrict__ mat1,
    const int* __restrict__ ed2, int E2r, int n2e, int sh2, int B2, int* __restrict__ mat2) {
  __shared__ int hist[256];
  int b = blockIdx.x;
  const int* ed; int Er, ne, sh, Bn, blk; int* mat;
  if (b < NB) { ed = ed1; Er = E1r; ne = n1e; sh = sh1; Bn = B1; mat = mat1; blk = b; }
  else { ed = ed2; Er = E2r; ne = n2e; sh = sh2; Bn = B2; mat = mat2; blk = b - NB; }
  for (int i = threadIdx.x; i < Bn; i += 256) hist[i] = 0;
  __syncthreads();
  int chunk = (ne + NB - 1) / NB;
  int lo = blk * chunk, hi = lo + chunk;
  if (hi > ne) hi = ne;
  for (int e = lo + threadIdx.x; e < hi; e += 256) {
    int d = (e < Er) ? ed[e] : (e - Er);
    atomicAdd(&hist[d >> sh], 1);  // LDS atomic
  }
  __syncthreads();
  for (int i = threadIdx.x; i < Bn; i += 256) mat[(size_t)i * NB + blk] = hist[i];
}

// ---------- scan chain ----------
__global__ __launch_bounds__(256) void scan_partial2(
    const int* __restrict__ cnt1, int n1, int* __restrict__ psum1, int* __restrict__ bsum1,
    const int* __restrict__ cnt2, int n2, int* __restrict__ psum2, int* __restrict__ bsum2,
    int split) {
  __shared__ int sh[256];
  int b = blockIdx.x;
  const int* cnt; int n; int* psum; int* bsum; int lb;
  if (b < split) { cnt = cnt1; n = n1; psum = psum1; bsum = bsum1; lb = b; }
  else { cnt = cnt2; n = n2; psum = psum2; bsum = bsum2; lb = b - split; }
  int i = lb * 256 + threadIdx.x;
  int tid = threadIdx.x;
  sh[tid] = (i < n) ? cnt[i] : 0;
  __syncthreads();
  for (int off = 1; off < 256; off <<= 1) {
    int t = (tid >= off) ? sh[tid - off] : 0;
    __syncthreads();
    if (tid >= off) sh[tid] += t;
    __syncthreads();
  }
  if (i < n) psum[i] = sh[tid];
  if (tid == 255) bsum[lb] = sh[255];
}

__global__ __launch_bounds__(256) void scan_bsums2(
    int* __restrict__ bsum1, int nb1, int* __restrict__ bsum2, int nb2) {
  __shared__ int sh[256];
  const int tid = threadIdx.x;
  for (int which = 0; which < 2; ++which) {
    int* bsum = which ? bsum2 : bsum1;
    int nb = which ? nb2 : nb1;
    int run = 0;
    for (int start = 0; start < nb; start += 256) {
      int i = start + tid;
      int v = (i < nb) ? bsum[i] : 0;
      __syncthreads();
      sh[tid] = v;
      __syncthreads();
      for (int off = 1; off < 256; off <<= 1) {
        int t = (tid >= off) ? sh[tid - off] : 0;
        __syncthreads();
        if (tid >= off) sh[tid] += t;
        __syncthreads();
      }
      if (i < nb) bsum[i] = run + sh[tid] - v;  // exclusive
      run += sh[255];
      __syncthreads();
    }
  }
}

__global__ __launch_bounds__(256) void finalize_excl2(
    const int* __restrict__ cnt1, const int* __restrict__ psum1,
    const int* __restrict__ bsum1, int n1, int* __restrict__ excl1,
    const int* __restrict__ cnt2, const int* __restrict__ psum2,
    const int* __restrict__ bsum2, int n2, int* __restrict__ excl2, int split) {
  int b = blockIdx.x;
  const int *cnt, *psum, *bsum; int n; int* excl; int lb;
  if (b < split) { cnt = cnt1; psum = psum1; bsum = bsum1; n = n1; excl = excl1; lb = b; }
  else { cnt = cnt2; psum = psum2; bsum = bsum2; n = n2; excl = excl2; lb = b - split; }
  int i = lb * 256 + threadIdx.x;
  if (i >= n) return;
  excl[i] = psum[i] + bsum[lb] - cnt[i];
}

// ---------- Pass C: partition edges into bucket order via private LDS cursors ----------
__global__ __launch_bounds__(256) void bucket_part(
    const int* __restrict__ es1, const int* __restrict__ ed1, int E1r, int n1e,
    int sh1, int B1, const int* __restrict__ excl1, unsigned* __restrict__ part1,
    const int* __restrict__ es2, const int* __restrict__ ed2, int E2r, int n2e,
    int sh2, int B2, const int* __restrict__ excl2, unsigned* __restrict__ part2) {
  __shared__ int cur[256];
  int b = blockIdx.x;
  const int *es, *ed, *excl; int Er, ne, sh, Bn, blk; unsigned* part;
  if (b < NB) { es = es1; ed = ed1; Er = E1r; ne = n1e; sh = sh1; Bn = B1; excl = excl1; part = part1; blk = b; }
  else { es = es2; ed = ed2; Er = E2r; ne = n2e; sh = sh2; Bn = B2; excl = excl2; part = part2; blk = b - NB; }
  for (int i = threadIdx.x; i < Bn; i += 256) cur[i] = excl[(size_t)i * NB + blk];
  __syncthreads();
  int chunk = (ne + NB - 1) / NB;
  int lo = blk * chunk, hi = lo + chunk;
  if (hi > ne) hi = ne;
  const unsigned lmask = (1u << sh) - 1u;
  for (int e = lo + threadIdx.x; e < hi; e += 256) {
    int s, d;
    if (e < Er) { s = es[e]; d = ed[e]; } else { s = e - Er; d = s; }
    int bkt = d >> sh;
    int pos = atomicAdd(&cur[bkt], 1);  // LDS atomic; (block,bucket) ranges disjoint
    part[pos] = (((unsigned)d & lmask) << 18) | (unsigned)s;
  }
}

// ---------- Pass D: per-bucket LDS counting sort -> row_ptr + csr ----------
__global__ __launch_bounds__(256) void bucket_sort(
    const unsigned* __restrict__ part1, const int* __restrict__ excl1,
    int n1e, int sh1, int B1, int nd1, int* __restrict__ rp1, int* __restrict__ csr1,
    const unsigned* __restrict__ part2, const int* __restrict__ excl2,
    int n2e, int sh2, int B2, int nd2, int* __restrict__ rp2, int* __restrict__ csr2) {
  __shared__ int cnt_s[512];
  __shared__ int scan_s[512];
  int b = blockIdx.x;
  const unsigned* part; const int* excl; int ne, sh, Bn, nd, bkt; int *rp, *csr;
  if (b < B1) { part = part1; excl = excl1; ne = n1e; sh = sh1; Bn = B1; nd = nd1; rp = rp1; csr = csr1; bkt = b; }
  else { part = part2; excl = excl2; ne = n2e; sh = sh2; Bn = B2; nd = nd2; rp = rp2; csr = csr2; bkt = b - B1; }
  const int tid = threadIdx.x;
  const int dbase = bkt << sh;
  const int R = 1 << sh;
  int rcap = nd - dbase;
  if (rcap > R) rcap = R;
  const int base = excl[(size_t)bkt * NB];
  const int endv = (bkt == Bn - 1) ? ne : excl[(size_t)(bkt + 1) * NB];

  cnt_s[tid] = 0; cnt_s[256 + tid] = 0;
  __syncthreads();
  for (int i = base + tid; i < endv; i += 256)
    atomicAdd(&cnt_s[part[i] >> 18], 1);
  __syncthreads();
  scan_s[tid] = cnt_s[tid];
  scan_s[256 + tid] = cnt_s[256 + tid];
  __syncthreads();
  for (int off = 1; off < 256; off <<= 1) {
    int t = (tid >= off) ? scan_s[tid - off] : 0;
    __syncthreads();
    if (tid >= off) scan_s[tid] += t;
    __syncthreads();
  }
  for (int off = 1; off < 256; off <<= 1) {
    int t = (tid >= off) ? scan_s[256 + tid - off] : 0;
    __syncthreads();
    if (tid >= off) scan_s[256 + tid] += t;
    __syncthreads();
  }
  int lowtot = scan_s[255];
  scan_s[256 + tid] += lowtot;
  __syncthreads();
  if (tid < rcap) rp[dbase + tid + 1] = base + scan_s[tid];
  if (256 + tid < rcap) rp[dbase + 256 + tid + 1] = base + scan_s[256 + tid];
  cnt_s[tid] = base + scan_s[tid] - cnt_s[tid];
  cnt_s[256 + tid] = base + scan_s[256 + tid] - cnt_s[256 + tid];
  if (tid == 0 && bkt == 0) rp[0] = 0;
  __syncthreads();
  for (int i = base + tid; i < endv; i += 256) {
    unsigned p = part[i];
    int dl = p >> 18;
    int pos = atomicAdd(&cnt_s[dl], 1);  // LDS atomic
    csr[pos] = (int)(p & 0x3FFFFu);
  }
}

// ---------- merged fused GATv2: single-fetch, degree-specialized ----------
// block < split: movie dsts; else user dsts. 4 dsts/block (1 per wave).
// Fast path (deg<=16, ~94% of users): one softmax, no flash state, no prefetch.
// Multi-round path: ping-pong v/v2 prefetch (no register copies).
// Gather byte-offset = (src<<7)|h2 via one v_lshl_or (no-carry OR).
__global__ __launch_bounds__(256) void gat_dst2(
    const int* __restrict__ rp1, const int* __restrict__ csr1,
    const __half* __restrict__ xl1, const float* __restrict__ xr1,
    const float* __restrict__ att1, const float* __restrict__ bias1,
    float* __restrict__ out1, int nd1,
    const int* __restrict__ rp2, const int* __restrict__ csr2,
    const __half* __restrict__ xl2, const float* __restrict__ xr2,
    const float* __restrict__ att2, const float* __restrict__ bias2,
    float* __restrict__ out2, int nd2, int split) {
  __shared__ __align__(16) float tile[4][EPR * 64];  // 4 waves x 4KB, private

  const int b = blockIdx.x;
  const int* rp; const int* csr; const __half* xl; const float *xr, *att, *bias;
  float* out; int nd, d0;
  if (b < split) {
    rp = rp1; csr = csr1; xl = xl1; xr = xr1; att = att1; bias = bias1;
    out = out1; nd = nd1; d0 = b * 4;
  } else {
    rp = rp2; csr = csr2; xl = xl2; xr = xr2; att = att2; bias = bias2;
    out = out2; nd = nd2; d0 = (b - split) * 4;
  }
  const int w = threadIdx.x >> 6;
  const int d = d0 + w;
  if (d >= nd) return;
  const int h = threadIdx.x & 63;
  const unsigned h2 = (unsigned)h * 2u;          // byte offset of feature h (fp16)
  const char* xlb = (const char*)xl;
  float* tl = tile[w];

  const float xr_h = xr[(size_t)d * H + h];
  const float a = att[h];
  const float a06 = 0.6f * a, a04 = 0.4f * a;
  const float bias_h = bias[h];
  const int beg = rp[d];
  const int end = rp[d + 1];

  const int r = h & 15;          // transpose: my edge row
  const int q = h >> 4;          // quarter of that row
  const int pr = (q << 2) ^ r;   // xor piece for transpose reads

  float o;  // pre-activation output

  if (end - beg <= EPR) {
    // ================= fast path: single round, plain softmax =================
    const int cnt = end - beg;   // may be 0 (isolated dst) -> out = bias
    float v[EPR];
#pragma unroll
    for (int qq = 0; qq < EPR / 4; ++qq) {
      if (qq * 4 < cnt) {  // wave-uniform
#pragma unroll
        for (int i = 0; i < 4; ++i) {
          const int k = qq * 4 + i;
          int j = k < cnt ? k : cnt - 1;   // clamped dup
          unsigned src = (unsigned)csr[beg + j];
          v[k] = __half2float(*(const __half*)(xlb + ((src << 7) | h2)));
        }
      }
    }
#pragma unroll
    for (int qq = 0; qq < EPR / 4; ++qq) {
      if (qq * 4 < cnt) {
#pragma unroll
        for (int i = 0; i < 4; ++i) {
          const int k = qq * 4 + i;
          float p = v[k] + xr_h;
          tl[(k << 6) | (h ^ (k << 2))] = fmaf(p, a06, fabsf(p) * a04);
        }
      }
    }
    const float4* t4 = (const float4*)tl;
    float t0 = 0.f, t1 = 0.f, t2 = 0.f, t3 = 0.f;
#pragma unroll
    for (int c = 0; c < 4; ++c) {
      float4 q4 = t4[(r << 4) | (pr ^ c)];
      t0 += q4.x; t1 += q4.y; t2 += q4.z; t3 += q4.w;
    }
    float t = (t0 + t1) + (t2 + t3);
    t += __shfl_xor(t, 16, 64);
    t += __shfl_xor(t, 32, 64);
    t = (r < cnt) ? t : -3.0e38f;

    float M = t;
#pragma unroll
    for (int mk = 1; mk <= 8; mk <<= 1) M = fmaxf(M, __shfl_xor(M, mk, 64));
    float e = __expf(t - M);
    float S = e;
#pragma unroll
    for (int mk = 1; mk <= 8; mk <<= 1) S += __shfl_xor(S, mk, 64);
    if (h < 16) tl[h] = e;

    float P = 0.f;
#pragma unroll
    for (int qq = 0; qq < EPR / 4; ++qq) {
      if (qq * 4 < cnt) {
        float4 w4 = ((const float4*)tl)[qq];
        P += w4.x * v[qq * 4 + 0];
        P += w4.y * v[qq * 4 + 1];
        P += w4.z * v[qq * 4 + 2];
        P += w4.w * v[qq * 4 + 3];
      }
    }
    o = P / (S + 1e-16f) + bias_h;
  } else {
    // ================= multi-round path: flash + ping-pong prefetch ===========
    float m = -3.0e38f, s = 0.f, acc = 0.f;
    int base = beg;
    float v[EPR], v2[EPR];

    // prologue: first round is full (end-beg > EPR)
#pragma unroll
    for (int k = 0; k < EPR; ++k) {
      unsigned src = (unsigned)csr[base + k];
      v[k] = __half2float(*(const __half*)(xlb + ((src << 7) | h2)));
    }

    // one round: consume vc (cnt edges at base), prefetch into vp; returns have_next
    auto round = [&](float (&vc)[EPR], float (&vp)[EPR]) -> bool {
      int cnt = end - base;
      if (cnt > EPR) cnt = EPR;
      // phase 1: scores into swizzled tile
#pragma unroll
      for (int qq = 0; qq < EPR / 4; ++qq) {
        if (qq * 4 < cnt) {
#pragma unroll
          for (int i = 0; i < 4; ++i) {
            const int k = qq * 4 + i;
            float p = vc[k] + xr_h;
            tl[(k << 6) | (h ^ (k << 2))] = fmaf(p, a06, fabsf(p) * a04);
          }
        }
      }
      // prefetch next round (overlaps softmax chain below)
      const int nbase = base + EPR;
      int ncnt = end - nbase;
      const bool have_next = ncnt > 0;
      if (ncnt > EPR) ncnt = EPR;
      if (have_next) {
#pragma unroll
        for (int qq = 0; qq < EPR / 4; ++qq) {
          if (qq * 4 < ncnt) {
#pragma unroll
            for (int i = 0; i < 4; ++i) {
              const int k = qq * 4 + i;
              int j = k < ncnt ? k : ncnt - 1;
              unsigned src = (unsigned)csr[nbase + j];
              vp[k] = __half2float(*(const __half*)(xlb + ((src << 7) | h2)));
            }
          }
        }
      }
      // transpose -> per-edge score
      const float4* t4 = (const float4*)tl;
      float t0 = 0.f, t1 = 0.f, t2 = 0.f, t3 = 0.f;
#pragma unroll
      for (int c = 0; c < 4; ++c) {
        float4 q4 = t4[(r << 4) | (pr ^ c)];
        t0 += q4.x; t1 += q4.y; t2 += q4.z; t3 += q4.w;
      }
      float t = (t0 + t1) + (t2 + t3);
      t += __shfl_xor(t, 16, 64);
      t += __shfl_xor(t, 32, 64);
      t = (r < cnt) ? t : -3.0e38f;

      float M = t;
#pragma unroll
      for (int mk = 1; mk <= 8; mk <<= 1) M = fmaxf(M, __shfl_xor(M, mk, 64));
      float e = __expf(t - M);
      float S = e;
#pragma unroll
      for (int mk = 1; mk <= 8; mk <<= 1) S += __shfl_xor(S, mk, 64);
      if (h < 16) tl[h] = e;

      float nm = fmaxf(m, M);
      float a_old = __expf(m - nm);
      float a_new = __expf(M - nm);
      float P = 0.f;
#pragma unroll
      for (int qq = 0; qq < EPR / 4; ++qq) {
        if (qq * 4 < cnt) {
          float4 w4 = ((const float4*)tl)[qq];
          P += w4.x * vc[qq * 4 + 0];
          P += w4.y * vc[qq * 4 + 1];
          P += w4.z * vc[qq * 4 + 2];
          P += w4.w * vc[qq * 4 + 3];
        }
      }
      s = s * a_old + S * a_new;
      acc = acc * a_old + P * a_new;
      m = nm;
      base = nbase;
      return have_next;
    };

    for (;;) {
      if (!round(v, v2)) break;   // consume v, prefetch v2
      if (!round(v2, v)) break;   // consume v2, prefetch v
    }
    o = acc / (s + 1e-16f) + bias_h;
  }

  out[(size_t)d * H + h] = selu_f(o);
}

// ---------- launch ----------
extern "C" void kernel_launch(void* const* d_in, const int* in_sizes, int n_in,
                              void* d_out, int out_size, void* d_ws, size_t ws_size,
                              hipStream_t stream) {
  const float* x_user = (const float*)d_in[0];
  const float* x_movie = (const float*)d_in[1];
  const int* e_u2m = (const int*)d_in[2];
  const int* e_m2u = (const int*)d_in[3];
  const float* Wl = (const float*)d_in[4];
  const float* bl = (const float*)d_in[5];
  const float* Wr = (const float*)d_in[6];
  const float* br = (const float*)d_in[7];
  const float* att = (const float*)d_in[8];
  const float* bias = (const float*)d_in[9];

  const int n_user = in_sizes[0] / H;
  const int n_movie = in_sizes[1] / H;
  const int E1 = in_sizes[2] / 2;  // user->movie (dst = movie)
  const int E2 = in_sizes[3] / 2;  // movie->user (dst = user)
  const int n_loop = n_user < n_movie ? n_user : n_movie;
  const int nE1 = E1 + n_loop;
  const int nE2 = E2 + n_loop;

  const int SHM = 7, SHU = 9;
  const int Bm = (n_movie + (1 << SHM) - 1) >> SHM;
  const int Bu = (n_user + (1 << SHU) - 1) >> SHU;
  const int nmatM = Bm * NB, nmatU = Bu * NB;
  const int nbm = (nmatM + 255) / 256, nbu = (nmatU + 255) / 256;

  float* ws = (float*)d_ws;
  size_t o = 0;
  __half* xl_u2m = (__half*)(ws + o); o += (size_t)n_user * H / 2;
  __half* xl_m2u = (__half*)(ws + o); o += (size_t)n_movie * H / 2;
  float* xr_u2m = ws + o; o += (size_t)n_movie * H;
  float* xr_m2u = ws + o; o += (size_t)n_user * H;

  int* matM  = (int*)(ws + o); o += nmatM;
  int* psumM = (int*)(ws + o); o += nmatM;
  int* exclM = (int*)(ws + o); o += nmatM;
  int* matU  = (int*)(ws + o); o += nmatU;
  int* psumU = (int*)(ws + o); o += nmatU;
  int* exclU = (int*)(ws + o); o += nmatU;
  int* bsumM = (int*)(ws + o); o += 1024;
  int* bsumU = (int*)(ws + o); o += 1024;
  unsigned* partM = (unsigned*)(ws + o); o += nE1;
  unsigned* partU = (unsigned*)(ws + o); o += nE2;
  int* csr1 = (int*)(ws + o); o += nE1;
  int* csr2 = (int*)(ws + o); o += nE2;
  int* rp1  = (int*)(ws + o); o += n_movie + 1;
  int* rp2  = (int*)(ws + o); o += n_user + 1;

  float* out_u = (float*)d_out;
  float* out_m = out_u + (size_t)n_user * H;

  const int gu = (n_user + 63) / 64;
  const int gm = (n_movie + 63) / 64;
  const int split1 = (n_movie + 3) / 4;   // gat: movie blocks (long, launch first)
  const int split2 = (n_user + 3) / 4;    // gat: user blocks

  // ---- CSR build: deterministic two-level bucket sort, zero device atomics ----
  bucket_hist<<<2 * NB, 256, 0, stream>>>(
      e_u2m + E1, E1, nE1, SHM, Bm, matM,
      e_m2u + E2, E2, nE2, SHU, Bu, matU);
  scan_partial2<<<nbm + nbu, 256, 0, stream>>>(
      matM, nmatM, psumM, bsumM, matU, nmatU, psumU, bsumU, nbm);
  scan_bsums2<<<1, 256, 0, stream>>>(bsumM, nbm, bsumU, nbu);
  finalize_excl2<<<nbm + nbu, 256, 0, stream>>>(
      matM, psumM, bsumM, nmatM, exclM,
      matU, psumU, bsumU, nmatU, exclU, nbm);
  bucket_part<<<2 * NB, 256, 0, stream>>>(
      e_u2m, e_u2m + E1, E1, nE1, SHM, Bm, exclM, partM,
      e_m2u, e_m2u + E2, E2, nE2, SHU, Bu, exclU, partU);
  bucket_sort<<<Bm + Bu, 256, 0, stream>>>(
      partM, exclM, nE1, SHM, Bm, n_movie, rp1, csr1,
      partU, exclU, nE2, SHU, Bu, n_user, rp2, csr2);

  for (int l = 0; l < 2; ++l) {
    const float* cu = (l == 0) ? x_user : out_u;
    const float* cm = (l == 0) ? x_movie : out_m;
    const int p0 = l * 2 + 0;  // user->movie params
    const int p1 = l * 2 + 1;  // movie->user params

    gemm64_dual2<<<gu + gm, 256, 0, stream>>>(
        cu, cm,
        Wl + (size_t)p0 * H * H, bl + (size_t)p0 * H,   // user C0 = Wl[p0] (fp16)
        Wr + (size_t)p1 * H * H, br + (size_t)p1 * H,   // user C1 = Wr[p1] (fp32)
        Wl + (size_t)p1 * H * H, bl + (size_t)p1 * H,   // movie C0 = Wl[p1] (fp16)
        Wr + (size_t)p0 * H * H, br + (size_t)p0 * H,   // movie C1 = Wr[p0] (fp32)
        xl_u2m, xr_m2u, xl_m2u, xr_u2m,
        n_user, n_movie, gu);

    gat_dst2<<<split1 + split2, 256, 0, stream>>>(
        rp1, csr1, xl_u2m, xr_u2m, att + (size_t)p0 * H, bias + (size_t)p0 * H,
        out_m, n_movie,
        rp2, csr2, xl_m2u, xr_m2u, att + (size_t)p1 * H, bias + (size_t)p1 * H,
        out_u, n_user, split1);
  }
}

// Round 13
// 437.570 us; speedup vs baseline: 1.5983x; 1.1035x over previous
//
#include <hip/hip_runtime.h>
#include <hip/hip_fp16.h>
#include <cstdint>

#define H 64
#define EPR 16   // edges per round in gat (16 -> 4KB tile/wave)
#define NB 120   // partition blocks per graph (pass A/C chunking)

__device__ __forceinline__ float selu_f(float x) {
  const float sc = 1.0507009873554805f;
  const float al = 1.6732632423543772f;
  return x > 0.f ? sc * x : sc * al * (expf(x) - 1.f);
}

// ---------- merged dual GEMM for both node sets (one launch per layer) ----------
__global__ __launch_bounds__(256) void gemm64_dual2(
    const float* __restrict__ Au, const float* __restrict__ Am,
    const float* __restrict__ W0u, const float* __restrict__ b0u,
    const float* __restrict__ W1u, const float* __restrict__ b1u,
    const float* __restrict__ W0m, const float* __restrict__ b0m,
    const float* __restrict__ W1m, const float* __restrict__ b1m,
    __half* __restrict__ C0u, float* __restrict__ C1u,
    __half* __restrict__ C0m, float* __restrict__ C1m,
    int Nu, int Nm, int split) {
  __shared__ float Ws0[64 * 64];
  __shared__ float Ws1[64 * 64];
  __shared__ float As[64][65];
  __shared__ float bs0[64], bs1[64];

  const float *A, *W0, *b0, *W1, *b1;
  __half* C0; float* C1; int N, blk;
  if (blockIdx.x < split) {
    A = Au; W0 = W0u; b0 = b0u; W1 = W1u; b1 = b1u;
    C0 = C0u; C1 = C1u; N = Nu; blk = blockIdx.x;
  } else {
    A = Am; W0 = W0m; b0 = b0m; W1 = W1m; b1 = b1m;
    C0 = C0m; C1 = C1m; N = Nm; blk = blockIdx.x - split;
  }

  const int tid = threadIdx.x;
  for (int i = tid; i < 1024; i += 256) {
    ((float4*)Ws0)[i] = ((const float4*)W0)[i];
    ((float4*)Ws1)[i] = ((const float4*)W1)[i];
  }
  if (tid < 64) { bs0[tid] = b0[tid]; bs1[tid] = b1[tid]; }

  const int row0 = blk * 64;
  for (int i = tid; i < 1024; i += 256) {
    int r = i >> 4, c4 = i & 15;
    int row = row0 + r;
    float4 v = make_float4(0.f, 0.f, 0.f, 0.f);
    if (row < N) v = ((const float4*)(A + (size_t)row * H))[c4];
    As[r][c4 * 4 + 0] = v.x;
    As[r][c4 * 4 + 1] = v.y;
    As[r][c4 * 4 + 2] = v.z;
    As[r][c4 * 4 + 3] = v.w;
  }
  __syncthreads();

  const int g = tid & 3;
  const int r = tid >> 2;
  float a0[16], a1[16];
#pragma unroll
  for (int j = 0; j < 16; ++j) { a0[j] = bs0[g * 16 + j]; a1[j] = bs1[g * 16 + j]; }

  for (int k = 0; k < 64; ++k) {
    float ak = As[r][k];
    const float4* w0r = (const float4*)&Ws0[k * 64 + g * 16];
    const float4* w1r = (const float4*)&Ws1[k * 64 + g * 16];
#pragma unroll
    for (int j4 = 0; j4 < 4; ++j4) {
      float4 w0 = w0r[j4], w1 = w1r[j4];
      a0[j4 * 4 + 0] += ak * w0.x; a0[j4 * 4 + 1] += ak * w0.y;
      a0[j4 * 4 + 2] += ak * w0.z; a0[j4 * 4 + 3] += ak * w0.w;
      a1[j4 * 4 + 0] += ak * w1.x; a1[j4 * 4 + 1] += ak * w1.y;
      a1[j4 * 4 + 2] += ak * w1.z; a1[j4 * 4 + 3] += ak * w1.w;
    }
  }

  const int row = row0 + r;
  if (row < N) {
    unsigned pu[8];
#pragma unroll
    for (int j2 = 0; j2 < 8; ++j2) {
      __half2 t = __floats2half2_rn(a0[2 * j2], a0[2 * j2 + 1]);
      pu[j2] = *(unsigned*)&t;
    }
    uint4* c0 = (uint4*)(C0 + (size_t)row * H + g * 16);
    c0[0] = make_uint4(pu[0], pu[1], pu[2], pu[3]);
    c0[1] = make_uint4(pu[4], pu[5], pu[6], pu[7]);

    float4* c1 = (float4*)(C1 + (size_t)row * H + g * 16);
#pragma unroll
    for (int j4 = 0; j4 < 4; ++j4) {
      c1[j4] = make_float4(a1[j4 * 4 + 0], a1[j4 * 4 + 1], a1[j4 * 4 + 2], a1[j4 * 4 + 3]);
    }
  }
}

// ---------- Pass A: per-block bucket histograms (LDS only, no device atomics) ----------
__global__ __launch_bounds__(256) void bucket_hist(
    const int* __restrict__ ed1, int E1r, int n1e, int sh1, int B1, int* __restrict__ mat1,
    const int* __restrict__ ed2, int E2r, int n2e, int sh2, int B2, int* __restrict__ mat2) {
  __shared__ int hist[640];
  int b = blockIdx.x;
  const int* ed; int Er, ne, sh, Bn, blk; int* mat;
  if (b < NB) { ed = ed1; Er = E1r; ne = n1e; sh = sh1; Bn = B1; mat = mat1; blk = b; }
  else { ed = ed2; Er = E2r; ne = n2e; sh = sh2; Bn = B2; mat = mat2; blk = b - NB; }
  for (int i = threadIdx.x; i < Bn; i += 256) hist[i] = 0;
  __syncthreads();
  int chunk = (ne + NB - 1) / NB;
  int lo = blk * chunk, hi = lo + chunk;
  if (hi > ne) hi = ne;
  for (int e = lo + threadIdx.x; e < hi; e += 256) {
    int d = (e < Er) ? ed[e] : (e - Er);
    atomicAdd(&hist[d >> sh], 1);  // LDS atomic
  }
  __syncthreads();
  for (int i = threadIdx.x; i < Bn; i += 256) mat[(size_t)i * NB + blk] = hist[i];
}

// ---------- scan chain ----------
__global__ __launch_bounds__(256) void scan_partial2(
    const int* __restrict__ cnt1, int n1, int* __restrict__ psum1, int* __restrict__ bsum1,
    const int* __restrict__ cnt2, int n2, int* __restrict__ psum2, int* __restrict__ bsum2,
    int split) {
  __shared__ int sh[256];
  int b = blockIdx.x;
  const int* cnt; int n; int* psum; int* bsum; int lb;
  if (b < split) { cnt = cnt1; n = n1; psum = psum1; bsum = bsum1; lb = b; }
  else { cnt = cnt2; n = n2; psum = psum2; bsum = bsum2; lb = b - split; }
  int i = lb * 256 + threadIdx.x;
  int tid = threadIdx.x;
  sh[tid] = (i < n) ? cnt[i] : 0;
  __syncthreads();
  for (int off = 1; off < 256; off <<= 1) {
    int t = (tid >= off) ? sh[tid - off] : 0;
    __syncthreads();
    if (tid >= off) sh[tid] += t;
    __syncthreads();
  }
  if (i < n) psum[i] = sh[tid];
  if (tid == 255) bsum[lb] = sh[255];
}

__global__ __launch_bounds__(256) void scan_bsums2(
    int* __restrict__ bsum1, int nb1, int* __restrict__ bsum2, int nb2) {
  __shared__ int sh[256];
  const int tid = threadIdx.x;
  for (int which = 0; which < 2; ++which) {
    int* bsum = which ? bsum2 : bsum1;
    int nb = which ? nb2 : nb1;
    int run = 0;
    for (int start = 0; start < nb; start += 256) {
      int i = start + tid;
      int v = (i < nb) ? bsum[i] : 0;
      __syncthreads();
      sh[tid] = v;
      __syncthreads();
      for (int off = 1; off < 256; off <<= 1) {
        int t = (tid >= off) ? sh[tid - off] : 0;
        __syncthreads();
        if (tid >= off) sh[tid] += t;
        __syncthreads();
      }
      if (i < nb) bsum[i] = run + sh[tid] - v;  // exclusive
      run += sh[255];
      __syncthreads();
    }
  }
}

__global__ __launch_bounds__(256) void finalize_excl2(
    const int* __restrict__ cnt1, const int* __restrict__ psum1,
    const int* __restrict__ bsum1, int n1, int* __restrict__ excl1,
    const int* __restrict__ cnt2, const int* __restrict__ psum2,
    const int* __restrict__ bsum2, int n2, int* __restrict__ excl2, int split) {
  int b = blockIdx.x;
  const int *cnt, *psum, *bsum; int n; int* excl; int lb;
  if (b < split) { cnt = cnt1; psum = psum1; bsum = bsum1; n = n1; excl = excl1; lb = b; }
  else { cnt = cnt2; psum = psum2; bsum = bsum2; n = n2; excl = excl2; lb = b - split; }
  int i = lb * 256 + threadIdx.x;
  if (i >= n) return;
  excl[i] = psum[i] + bsum[lb] - cnt[i];
}

// ---------- Pass C: partition edges into bucket order via private LDS cursors ----------
__global__ __launch_bounds__(256) void bucket_part(
    const int* __restrict__ es1, const int* __restrict__ ed1, int E1r, int n1e,
    int sh1, int B1, const int* __restrict__ excl1, unsigned* __restrict__ part1,
    const int* __restrict__ es2, const int* __restrict__ ed2, int E2r, int n2e,
    int sh2, int B2, const int* __restrict__ excl2, unsigned* __restrict__ part2) {
  __shared__ int cur[640];
  int b = blockIdx.x;
  const int *es, *ed, *excl; int Er, ne, sh, Bn, blk; unsigned* part;
  if (b < NB) { es = es1; ed = ed1; Er = E1r; ne = n1e; sh = sh1; Bn = B1; excl = excl1; part = part1; blk = b; }
  else { es = es2; ed = ed2; Er = E2r; ne = n2e; sh = sh2; Bn = B2; excl = excl2; part = part2; blk = b - NB; }
  for (int i = threadIdx.x; i < Bn; i += 256) cur[i] = excl[(size_t)i * NB + blk];
  __syncthreads();
  int chunk = (ne + NB - 1) / NB;
  int lo = blk * chunk, hi = lo + chunk;
  if (hi > ne) hi = ne;
  const unsigned lmask = (1u << sh) - 1u;
  for (int e = lo + threadIdx.x; e < hi; e += 256) {
    int s, d;
    if (e < Er) { s = es[e]; d = ed[e]; } else { s = e - Er; d = s; }
    int bkt = d >> sh;
    int pos = atomicAdd(&cur[bkt], 1);  // LDS atomic; (block,bucket) ranges disjoint
    part[pos] = (((unsigned)d & lmask) << 18) | (unsigned)s;
  }
}

// ---------- Pass D: per-bucket LDS counting sort (R<=256) -> row_ptr + csr ----------
__global__ __launch_bounds__(256) void bucket_sort(
    const unsigned* __restrict__ part1, const int* __restrict__ excl1,
    int n1e, int sh1, int B1, int nd1, int* __restrict__ rp1, int* __restrict__ csr1,
    const unsigned* __restrict__ part2, const int* __restrict__ excl2,
    int n2e, int sh2, int B2, int nd2, int* __restrict__ rp2, int* __restrict__ csr2) {
  __shared__ int cnt_s[256];
  __shared__ int scan_s[256];
  int b = blockIdx.x;
  const unsigned* part; const int* excl; int ne, sh, Bn, nd, bkt; int *rp, *csr;
  if (b < B1) { part = part1; excl = excl1; ne = n1e; sh = sh1; Bn = B1; nd = nd1; rp = rp1; csr = csr1; bkt = b; }
  else { part = part2; excl = excl2; ne = n2e; sh = sh2; Bn = B2; nd = nd2; rp = rp2; csr = csr2; bkt = b - B1; }
  const int tid = threadIdx.x;
  const int dbase = bkt << sh;
  const int R = 1 << sh;          // <= 256
  int rcap = nd - dbase;
  if (rcap > R) rcap = R;
  const int base = excl[(size_t)bkt * NB];
  const int endv = (bkt == Bn - 1) ? ne : excl[(size_t)(bkt + 1) * NB];

  cnt_s[tid] = 0;
  __syncthreads();
  for (int i = base + tid; i < endv; i += 256)
    atomicAdd(&cnt_s[part[i] >> 18], 1);
  __syncthreads();
  int c = cnt_s[tid];
  scan_s[tid] = c;
  __syncthreads();
  for (int off = 1; off < 256; off <<= 1) {
    int t = (tid >= off) ? scan_s[tid - off] : 0;
    __syncthreads();
    if (tid >= off) scan_s[tid] += t;
    __syncthreads();
  }
  if (tid < rcap) rp[dbase + tid + 1] = base + scan_s[tid];
  cnt_s[tid] = base + scan_s[tid] - c;   // exclusive write cursor
  if (tid == 0 && bkt == 0) rp[0] = 0;
  __syncthreads();
  for (int i = base + tid; i < endv; i += 256) {
    unsigned p = part[i];
    int dl = p >> 18;
    int pos = atomicAdd(&cnt_s[dl], 1);  // LDS atomic
    csr[pos] = (int)(p & 0x3FFFFu);
  }
}

// ---------- merged fused GATv2: single-fetch, degree-specialized ----------
// block < split: movie dsts; else user dsts. 4 dsts/block (1 per wave).
// csr indices fetched through the SCALAR cache (uniform base via readfirstlane,
// uniform offsets -> s_load_dwordx4/x8): one scalar fetch replaces 16 broadcast
// vector loads per round; feature gathers stay independent vector loads.
__global__ __launch_bounds__(256) void gat_dst2(
    const int* __restrict__ rp1, const int* __restrict__ csr1,
    const __half* __restrict__ xl1, const float* __restrict__ xr1,
    const float* __restrict__ att1, const float* __restrict__ bias1,
    float* __restrict__ out1, int nd1,
    const int* __restrict__ rp2, const int* __restrict__ csr2,
    const __half* __restrict__ xl2, const float* __restrict__ xr2,
    const float* __restrict__ att2, const float* __restrict__ bias2,
    float* __restrict__ out2, int nd2, int split) {
  __shared__ __align__(16) float tile[4][EPR * 64];  // 4 waves x 4KB, private

  const int b = blockIdx.x;
  const int* rp; const int* csr; const __half* xl; const float *xr, *att, *bias;
  float* out; int nd, d0;
  if (b < split) {
    rp = rp1; csr = csr1; xl = xl1; xr = xr1; att = att1; bias = bias1;
    out = out1; nd = nd1; d0 = b * 4;
  } else {
    rp = rp2; csr = csr2; xl = xl2; xr = xr2; att = att2; bias = bias2;
    out = out2; nd = nd2; d0 = (b - split) * 4;
  }
  const int w = threadIdx.x >> 6;
  const int d = d0 + w;
  if (d >= nd) return;
  const int h = threadIdx.x & 63;
  const unsigned h2 = (unsigned)h * 2u;          // byte offset of feature h (fp16)
  const char* xlb = (const char*)xl;
  float* tl = tile[w];

  const float xr_h = xr[(size_t)d * H + h];
  const float a = att[h];
  const float a06 = 0.6f * a, a04 = 0.4f * a;
  const float bias_h = bias[h];
  // wave-uniform bounds -> SGPRs (enables s_load for csr index fetches)
  const int sbeg = __builtin_amdgcn_readfirstlane(rp[d]);
  const int send = __builtin_amdgcn_readfirstlane(rp[d + 1]);

  const int r = h & 15;          // transpose: my edge row
  const int q = h >> 4;          // quarter of that row
  const int pr = (q << 2) ^ r;   // xor piece for transpose reads

  float o;  // pre-activation output

  if (send - sbeg <= EPR) {
    // ================= fast path: single round, plain softmax =================
    const int cnt = send - sbeg;   // may be 0 (isolated dst) -> out = bias
    const int* csw = csr + sbeg;   // uniform base -> scalar loads
    float v[EPR];
#pragma unroll
    for (int qq = 0; qq < EPR / 4; ++qq) {
      if (qq * 4 < cnt) {  // wave-uniform
#pragma unroll
        for (int i = 0; i < 4; ++i) {
          const int k = qq * 4 + i;
          int j = k < cnt ? k : cnt - 1;   // uniform clamped dup
          unsigned src = (unsigned)csw[j]; // s_load (uniform addr)
          v[k] = __half2float(*(const __half*)(xlb + ((src << 7) | h2)));
        }
      }
    }
#pragma unroll
    for (int qq = 0; qq < EPR / 4; ++qq) {
      if (qq * 4 < cnt) {
#pragma unroll
        for (int i = 0; i < 4; ++i) {
          const int k = qq * 4 + i;
          float p = v[k] + xr_h;
          tl[(k << 6) | (h ^ (k << 2))] = fmaf(p, a06, fabsf(p) * a04);
        }
      }
    }
    const float4* t4 = (const float4*)tl;
    float t0 = 0.f, t1 = 0.f, t2 = 0.f, t3 = 0.f;
#pragma unroll
    for (int c = 0; c < 4; ++c) {
      float4 q4 = t4[(r << 4) | (pr ^ c)];
      t0 += q4.x; t1 += q4.y; t2 += q4.z; t3 += q4.w;
    }
    float t = (t0 + t1) + (t2 + t3);
    t += __shfl_xor(t, 16, 64);
    t += __shfl_xor(t, 32, 64);
    t = (r < cnt) ? t : -3.0e38f;

    float M = t;
#pragma unroll
    for (int mk = 1; mk <= 8; mk <<= 1) M = fmaxf(M, __shfl_xor(M, mk, 64));
    float e = __expf(t - M);
    float S = e;
#pragma unroll
    for (int mk = 1; mk <= 8; mk <<= 1) S += __shfl_xor(S, mk, 64);
    if (h < 16) tl[h] = e;

    float P = 0.f;
#pragma unroll
    for (int qq = 0; qq < EPR / 4; ++qq) {
      if (qq * 4 < cnt) {
        float4 w4 = ((const float4*)tl)[qq];
        P += w4.x * v[qq * 4 + 0];
        P += w4.y * v[qq * 4 + 1];
        P += w4.z * v[qq * 4 + 2];
        P += w4.w * v[qq * 4 + 3];
      }
    }
    o = P / (S + 1e-16f) + bias_h;
  } else {
    // ================= multi-round path: flash + ping-pong prefetch ===========
    float m = -3.0e38f, s = 0.f, acc = 0.f;
    int base = sbeg;               // uniform
    float v[EPR], v2[EPR];

    // prologue: first round is full (send-sbeg > EPR)
    {
      const int* csw = csr + base;
#pragma unroll
      for (int k = 0; k < EPR; ++k) {
        unsigned src = (unsigned)csw[k];   // s_load
        v[k] = __half2float(*(const __half*)(xlb + ((src << 7) | h2)));
      }
    }

    // one round: consume vc (cnt edges at base), prefetch into vp
    auto round = [&](float (&vc)[EPR], float (&vp)[EPR]) -> bool {
      int cnt = send - base;
      if (cnt > EPR) cnt = EPR;
#pragma unroll
      for (int qq = 0; qq < EPR / 4; ++qq) {
        if (qq * 4 < cnt) {
#pragma unroll
          for (int i = 0; i < 4; ++i) {
            const int k = qq * 4 + i;
            float p = vc[k] + xr_h;
            tl[(k << 6) | (h ^ (k << 2))] = fmaf(p, a06, fabsf(p) * a04);
          }
        }
      }
      // prefetch next round (overlaps softmax chain below)
      const int nbase = base + EPR;
      int ncnt = send - nbase;
      const bool have_next = ncnt > 0;
      if (ncnt > EPR) ncnt = EPR;
      if (have_next) {
        const int* csn = csr + nbase;      // uniform base -> scalar loads
#pragma unroll
        for (int qq = 0; qq < EPR / 4; ++qq) {
          if (qq * 4 < ncnt) {
#pragma unroll
            for (int i = 0; i < 4; ++i) {
              const int k = qq * 4 + i;
              int j = k < ncnt ? k : ncnt - 1;
              unsigned src = (unsigned)csn[j];
              vp[k] = __half2float(*(const __half*)(xlb + ((src << 7) | h2)));
            }
          }
        }
      }
      const float4* t4 = (const float4*)tl;
      float t0 = 0.f, t1 = 0.f, t2 = 0.f, t3 = 0.f;
#pragma unroll
      for (int c = 0; c < 4; ++c) {
        float4 q4 = t4[(r << 4) | (pr ^ c)];
        t0 += q4.x; t1 += q4.y; t2 += q4.z; t3 += q4.w;
      }
      float t = (t0 + t1) + (t2 + t3);
      t += __shfl_xor(t, 16, 64);
      t += __shfl_xor(t, 32, 64);
      t = (r < cnt) ? t : -3.0e38f;

      float M = t;
#pragma unroll
      for (int mk = 1; mk <= 8; mk <<= 1) M = fmaxf(M, __shfl_xor(M, mk, 64));
      float e = __expf(t - M);
      float S = e;
#pragma unroll
      for (int mk = 1; mk <= 8; mk <<= 1) S += __shfl_xor(S, mk, 64);
      if (h < 16) tl[h] = e;

      float nm = fmaxf(m, M);
      float a_old = __expf(m - nm);
      float a_new = __expf(M - nm);
      float P = 0.f;
#pragma unroll
      for (int qq = 0; qq < EPR / 4; ++qq) {
        if (qq * 4 < cnt) {
          float4 w4 = ((const float4*)tl)[qq];
          P += w4.x * vc[qq * 4 + 0];
          P += w4.y * vc[qq * 4 + 1];
          P += w4.z * vc[qq * 4 + 2];
          P += w4.w * vc[qq * 4 + 3];
        }
      }
      s = s * a_old + S * a_new;
      acc = acc * a_old + P * a_new;
      m = nm;
      base = nbase;
      return have_next;
    };

    for (;;) {
      if (!round(v, v2)) break;   // consume v, prefetch v2
      if (!round(v2, v)) break;   // consume v2, prefetch v
    }
    o = acc / (s + 1e-16f) + bias_h;
  }

  out[(size_t)d * H + h] = selu_f(o);
}

// ---------- launch ----------
extern "C" void kernel_launch(void* const* d_in, const int* in_sizes, int n_in,
                              void* d_out, int out_size, void* d_ws, size_t ws_size,
                              hipStream_t stream) {
  const float* x_user = (const float*)d_in[0];
  const float* x_movie = (const float*)d_in[1];
  const int* e_u2m = (const int*)d_in[2];
  const int* e_m2u = (const int*)d_in[3];
  const float* Wl = (const float*)d_in[4];
  const float* bl = (const float*)d_in[5];
  const float* Wr = (const float*)d_in[6];
  const float* br = (const float*)d_in[7];
  const float* att = (const float*)d_in[8];
  const float* bias = (const float*)d_in[9];

  const int n_user = in_sizes[0] / H;
  const int n_movie = in_sizes[1] / H;
  const int E1 = in_sizes[2] / 2;  // user->movie (dst = movie)
  const int E2 = in_sizes[3] / 2;  // movie->user (dst = user)
  const int n_loop = n_user < n_movie ? n_user : n_movie;
  const int nE1 = E1 + n_loop;
  const int nE2 = E2 + n_loop;

  // smaller buckets -> 4x more pass-D blocks (SHM 5: 32 dsts, SHU 8: 256 dsts)
  const int SHM = 5, SHU = 8;
  const int Bm = (n_movie + (1 << SHM) - 1) >> SHM;   // ~625
  const int Bu = (n_user + (1 << SHU) - 1) >> SHU;    // ~391
  const int nmatM = Bm * NB, nmatU = Bu * NB;
  const int nbm = (nmatM + 255) / 256, nbu = (nmatU + 255) / 256;

  float* ws = (float*)d_ws;
  size_t o = 0;
  __half* xl_u2m = (__half*)(ws + o); o += (size_t)n_user * H / 2;
  __half* xl_m2u = (__half*)(ws + o); o += (size_t)n_movie * H / 2;
  float* xr_u2m = ws + o; o += (size_t)n_movie * H;
  float* xr_m2u = ws + o; o += (size_t)n_user * H;

  int* matM  = (int*)(ws + o); o += nmatM;
  int* psumM = (int*)(ws + o); o += nmatM;
  int* exclM = (int*)(ws + o); o += nmatM;
  int* matU  = (int*)(ws + o); o += nmatU;
  int* psumU = (int*)(ws + o); o += nmatU;
  int* exclU = (int*)(ws + o); o += nmatU;
  int* bsumM = (int*)(ws + o); o += 1024;
  int* bsumU = (int*)(ws + o); o += 1024;
  unsigned* partM = (unsigned*)(ws + o); o += nE1;
  unsigned* partU = (unsigned*)(ws + o); o += nE2;
  int* csr1 = (int*)(ws + o); o += nE1;
  int* csr2 = (int*)(ws + o); o += nE2;
  int* rp1  = (int*)(ws + o); o += n_movie + 1;
  int* rp2  = (int*)(ws + o); o += n_user + 1;

  float* out_u = (float*)d_out;
  float* out_m = out_u + (size_t)n_user * H;

  const int gu = (n_user + 63) / 64;
  const int gm = (n_movie + 63) / 64;
  const int split1 = (n_movie + 3) / 4;   // gat: movie blocks (long, launch first)
  const int split2 = (n_user + 3) / 4;    // gat: user blocks

  // ---- CSR build: deterministic two-level bucket sort, zero device atomics ----
  bucket_hist<<<2 * NB, 256, 0, stream>>>(
      e_u2m + E1, E1, nE1, SHM, Bm, matM,
      e_m2u + E2, E2, nE2, SHU, Bu, matU);
  scan_partial2<<<nbm + nbu, 256, 0, stream>>>(
      matM, nmatM, psumM, bsumM, matU, nmatU, psumU, bsumU, nbm);
  scan_bsums2<<<1, 256, 0, stream>>>(bsumM, nbm, bsumU, nbu);
  finalize_excl2<<<nbm + nbu, 256, 0, stream>>>(
      matM, psumM, bsumM, nmatM, exclM,
      matU, psumU, bsumU, nmatU, exclU, nbm);
  bucket_part<<<2 * NB, 256, 0, stream>>>(
      e_u2m, e_u2m + E1, E1, nE1, SHM, Bm, exclM, partM,
      e_m2u, e_m2u + E2, E2, nE2, SHU, Bu, exclU, partU);
  bucket_sort<<<Bm + Bu, 256, 0, stream>>>(
      partM, exclM, nE1, SHM, Bm, n_movie, rp1, csr1,
      partU, exclU, nE2, SHU, Bu, n_user, rp2, csr2);

  for (int l = 0; l < 2; ++l) {
    const float* cu = (l == 0) ? x_user : out_u;
    const float* cm = (l == 0) ? x_movie : out_m;
    const int p0 = l * 2 + 0;  // user->movie params
    const int p1 = l * 2 + 1;  // movie->user params

    gemm64_dual2<<<gu + gm, 256, 0, stream>>>(
        cu, cm,
        Wl + (size_t)p0 * H * H, bl + (size_t)p0 * H,   // user C0 = Wl[p0] (fp16)
        Wr + (size_t)p1 * H * H, br + (size_t)p1 * H,   // user C1 = Wr[p1] (fp32)
        Wl + (size_t)p1 * H * H, bl + (size_t)p1 * H,   // movie C0 = Wl[p1] (fp16)
        Wr + (size_t)p0 * H * H, br + (size_t)p0 * H,   // movie C1 = Wr[p0] (fp32)
        xl_u2m, xr_m2u, xl_m2u, xr_u2m,
        n_user, n_movie, gu);

    gat_dst2<<<split1 + split2, 256, 0, stream>>>(
        rp1, csr1, xl_u2m, xr_u2m, att + (size_t)p0 * H, bias + (size_t)p0 * H,
        out_m, n_movie,
        rp2, csr2, xl_m2u, xr_m2u, att + (size_t)p1 * H, bias + (size_t)p1 * H,
        out_u, n_user, split1);
  }
}